// Round 7
// baseline (48.955 us; speedup 1.0000x reference)
//
#include <hip/hip_runtime.h>

#define N  4096
#define ON 4090
#define NN (N * N)

// Direct register-blocked 7x7 valid conv. No LDS, no barriers.
// Thread -> 4-wide x 8-tall output strip. Block (256 thr) -> 64 x 128 tile.
// Input (64 MiB) is L3-resident; per-block window is L2/L1-warm, so the
// 4.4x read redundancy is absorbed by the cache hierarchy, not HBM.
__global__ __launch_bounds__(256, 8)
void conv7x7_direct(const float* __restrict__ x,
                    const float* __restrict__ w,
                    const float* __restrict__ bias,
                    float* __restrict__ out)
{
    const int tid = threadIdx.x;
    const int tau = tid & 15;            // 0..15 -> 4-wide col chunk
    const int rg  = tid >> 4;            // 0..15 -> 8-tall row group
    const int x0  = blockIdx.x * 64;
    const int y0  = blockIdx.y * 128;
    const int ox  = x0 + (tau << 2);     // output col base (mult of 4)
    const int oy0 = y0 + (rg << 3);      // output row base

    // weights/bias: uniform addresses -> scalar loads, live in SGPRs
    float ws[49];
    #pragma unroll
    for (int i = 0; i < 49; ++i) ws[i] = w[i];
    const float bv = bias[0];

    float acc[8][4] = {};

    #pragma unroll
    for (int rr = 0; rr < 14; ++rr) {    // 14 input rows feed 8 output rows
        const int gy = min(oy0 + rr, N - 1);          // row clamp (edge blocks)
        const int lb = (gy << 12) + ox;               // linear idx, fits int32
        // memory-safety clamps: engage only for threads whose affected
        // outputs are store-guarded (analysis: garbage feeds oy/ox >= 4090)
        const int l1 = min(lb + 4, NN - 4);           // stays 16B-aligned
        const int l2 = min(lb + 8, NN - 2);           // stays  8B-aligned

        float v[10];
        const float4 a = *reinterpret_cast<const float4*>(x + lb);
        const float4 b = *reinterpret_cast<const float4*>(x + l1);
        const float2 c = *reinterpret_cast<const float2*>(x + l2);
        v[0]=a.x; v[1]=a.y; v[2]=a.z; v[3]=a.w;
        v[4]=b.x; v[5]=b.y; v[6]=b.z; v[7]=b.w;
        v[8]=c.x; v[9]=c.y;

        #pragma unroll
        for (int r = 0; r < 8; ++r) {
            const int ky = rr - r;                    // compile-time after unroll
            if (ky >= 0 && ky < 7) {
                #pragma unroll
                for (int kx = 0; kx < 7; ++kx) {
                    const float wk = ws[ky * 7 + kx];
                    #pragma unroll
                    for (int j = 0; j < 4; ++j)
                        acc[r][j] = fmaf(v[kx + j], wk, acc[r][j]);
                }
            }
        }
    }

    // ---- store: unguarded float2 pairs interior, guarded scalar on edges ----
    if (ox + 4 <= ON && oy0 + 8 <= ON) {
        #pragma unroll
        for (int r = 0; r < 8; ++r) {
            float* dst = out + (size_t)(oy0 + r) * ON + ox;   // 8B-aligned
            *reinterpret_cast<float2*>(dst)     = make_float2(acc[r][0] + bv, acc[r][1] + bv);
            *reinterpret_cast<float2*>(dst + 2) = make_float2(acc[r][2] + bv, acc[r][3] + bv);
        }
    } else {
        #pragma unroll
        for (int r = 0; r < 8; ++r) {
            const int oy = oy0 + r;
            if (oy < ON) {
                float* dst = out + (size_t)oy * ON;
                #pragma unroll
                for (int j = 0; j < 4; ++j) {
                    const int oxj = ox + j;
                    if (oxj < ON) dst[oxj] = acc[r][j] + bv;
                }
            }
        }
    }
}

extern "C" void kernel_launch(void* const* d_in, const int* in_sizes, int n_in,
                              void* d_out, int out_size, void* d_ws, size_t ws_size,
                              hipStream_t stream) {
    const float* x    = (const float*)d_in[0];
    const float* w    = (const float*)d_in[1];
    const float* bias = (const float*)d_in[2];
    float* out        = (float*)d_out;

    dim3 grid((ON + 63) / 64, (ON + 127) / 128);   // 64 x 32 = 2048 blocks
    conv7x7_direct<<<grid, dim3(256, 1, 1), 0, stream>>>(x, w, bias, out);
}

// Round 8
// 40.146 us; speedup vs baseline: 1.2194x; 1.2194x over previous
//
#include <hip/hip_runtime.h>

#define TILE_W 128
#define TILE_H 32
#define HALO   6
#define IN_H   (TILE_H + HALO)   // 38 input rows
#define LDS_W  136               // 134 used, +2 pad (rows stay 16B-aligned)
#define N  4096
#define ON 4090

// width-4 global->LDS: each lane moves 4 B; LDS fill = 256 B/instr = 2 dwords
// per bank -> conflict-free (2-way aliasing is free). width-16 put 8 dwords
// per bank per instr and cost ~70 conflict cycles/instr (R4/R6 profile).
__device__ __forceinline__ void gload_lds4(const float* g, float* l) {
    __builtin_amdgcn_global_load_lds(
        (const __attribute__((address_space(1))) void*)g,
        (__attribute__((address_space(3))) void*)l,
        4, 0, 0);   // dest = uniform base + lane*4
}

__global__ __launch_bounds__(256, 7)
void conv7x7_kernel(const float* __restrict__ x,
                    const float* __restrict__ w,
                    const float* __restrict__ bias,
                    float* __restrict__ out)
{
    __shared__ float tile[IN_H][LDS_W];   // 20,672 B -> 7 blocks/CU

    const int tid  = threadIdx.x;
    const int lane = tid & 63;
    const int wv   = tid >> 6;
    const int x0   = blockIdx.x * TILE_W;
    const int y0   = blockIdx.y * TILE_H;

    // ---- stage 38 x 134 tile, per-row segments of 64/64/6 lanes ----
    // cols x0+lane (<=4031) and x0+64+lane (<=4095) are always in-bounds;
    // segment 3 clamps (clamped data only feeds store-guarded outputs).
    {
        const int gx2 = min(x0 + 128 + lane, N - 1);
        for (int r = wv; r < IN_H; r += 4) {
            const int gy = min(y0 + r, N - 1);
            const float* rowp = x + ((size_t)gy << 12);
            gload_lds4(rowp + x0 + lane,      &tile[r][0]);
            gload_lds4(rowp + x0 + 64 + lane, &tile[r][64]);
            if (lane < HALO)
                gload_lds4(rowp + gx2,        &tile[r][128]);
        }
    }

    // uniform-address weight/bias loads (scalar path) overlap staging
    float ws[49];
    #pragma unroll
    for (int i = 0; i < 49; ++i) ws[i] = w[i];
    const float bv = bias[0];

    __syncthreads();   // drains vmcnt before s_barrier

    // ---- compute: thread = (colchunk tau, rowgroup rg); 4-wide x 4-tall ----
    // lane-contiguous b128 reads: 32 lanes x 16 B contiguous -> conflict-free
    const int tau   = tid & 31;          // cols 4*tau .. 4*tau+3
    const int rg    = tid >> 5;          // rows 4*rg .. 4*rg+3
    const int colf  = tau << 2;
    const int rbase = rg << 2;

    float acc[4][4] = {};

    #pragma unroll
    for (int rr = 0; rr < 10; ++rr) {    // 10 input rows feed 4 output rows
        const float* rp = &tile[rbase + rr][colf];
        float v[10];
        const float4 a = *reinterpret_cast<const float4*>(rp);
        const float4 b = *reinterpret_cast<const float4*>(rp + 4);
        const float2 c = *reinterpret_cast<const float2*>(rp + 8);
        v[0]=a.x; v[1]=a.y; v[2]=a.z; v[3]=a.w;
        v[4]=b.x; v[5]=b.y; v[6]=b.z; v[7]=b.w;
        v[8]=c.x; v[9]=c.y;

        #pragma unroll
        for (int r = 0; r < 4; ++r) {
            const int ky = rr - r;               // compile-time after unroll
            if (ky >= 0 && ky < 7) {
                #pragma unroll
                for (int kx = 0; kx < 7; ++kx) {
                    const float wk = ws[ky * 7 + kx];
                    #pragma unroll
                    for (int j = 0; j < 4; ++j)
                        acc[r][j] = fmaf(v[kx + j], wk, acc[r][j]);
                }
            }
        }
    }

    // ---- store: unguarded float2 pairs interior, guarded scalar on edges ----
    const int ox  = x0 + colf;
    const int oy0 = y0 + rbase;
    if (ox + 4 <= ON && oy0 + 4 <= ON) {
        #pragma unroll
        for (int r = 0; r < 4; ++r) {
            float* dst = out + (size_t)(oy0 + r) * ON + ox;   // 8B-aligned
            *reinterpret_cast<float2*>(dst)     = make_float2(acc[r][0] + bv, acc[r][1] + bv);
            *reinterpret_cast<float2*>(dst + 2) = make_float2(acc[r][2] + bv, acc[r][3] + bv);
        }
    } else {
        #pragma unroll
        for (int r = 0; r < 4; ++r) {
            const int oy = oy0 + r;
            if (oy < ON) {
                float* dst = out + (size_t)oy * ON;
                #pragma unroll
                for (int j = 0; j < 4; ++j) {
                    const int oxj = ox + j;
                    if (oxj < ON) dst[oxj] = acc[r][j] + bv;
                }
            }
        }
    }
}

extern "C" void kernel_launch(void* const* d_in, const int* in_sizes, int n_in,
                              void* d_out, int out_size, void* d_ws, size_t ws_size,
                              hipStream_t stream) {
    const float* x    = (const float*)d_in[0];
    const float* w    = (const float*)d_in[1];
    const float* bias = (const float*)d_in[2];
    float* out        = (float*)d_out;

    dim3 grid((ON + TILE_W - 1) / TILE_W, (ON + TILE_H - 1) / TILE_H);  // 32 x 128
    conv7x7_kernel<<<grid, dim3(256, 1, 1), 0, stream>>>(x, w, bias, out);
}

// Round 9
// 34.151 us; speedup vs baseline: 1.4335x; 1.1755x over previous
//
#include <hip/hip_runtime.h>

#define TILE_W 128
#define TILE_H 32
#define HALO   6
#define IN_H   (TILE_H + HALO)          // 38 input rows
#define LDS_W  136                      // 134 needed, padded (mult of 4)
#define CPR    (LDS_W / 4)              // 34 float4-chunks per row
#define TILE_CHUNKS (IN_H * CPR)        // 1292
#define STAGE_INSTR ((TILE_CHUNKS + 63) / 64)   // 21
#define LDS_FLOATS  (STAGE_INSTR * 64 * 4)      // 5376 floats = 21504 B
#define N  4096
#define ON 4090
#define GX 32                           // tiles per output row
#define NWG (GX * 128)                  // 4096 blocks
#define CHUNK (NWG / 8)                 // 512 tiles per XCD

__device__ __forceinline__ void gload_lds16(const float* g, float* l) {
    __builtin_amdgcn_global_load_lds(
        (const __attribute__((address_space(1))) void*)g,
        (__attribute__((address_space(3))) void*)l,
        16, 0, 0);   // 16 B per lane, dest = uniform base + lane*16
}

__global__ __launch_bounds__(256, 7)
void conv7x7_kernel(const float* __restrict__ x,
                    const float* __restrict__ w,
                    const float* __restrict__ bias,
                    float* __restrict__ out)
{
    __shared__ float tile[LDS_FLOATS];   // 21,504 B -> 7 blocks/CU

    // XCD-chunked swizzle: HW round-robins dispatch id over 8 XCDs, so
    // giving XCD k the contiguous tile range [512k, 512(k+1)) keeps x- and
    // y-neighbor tiles on the same L2 -> partial-line write merge + halo reuse.
    const int d  = blockIdx.x;
    const int t  = (d & 7) * CHUNK + (d >> 3);
    const int bx = t & (GX - 1);
    const int by = t >> 5;

    const int tid  = threadIdx.x;
    const int lane = tid & 63;
    const int wv   = tid >> 6;
    const int x0   = bx * TILE_W;
    const int y0   = by * TILE_H;

    // ---- stage 38 x 134(+pad) tile: flat float4-chunk order, 1 KiB/instr ----
    {
        const int xc0 = x0 >> 2;                  // global chunk col base
        for (int k = wv; k < STAGE_INSTR; k += 4) {
            const int m   = (k << 6) + lane;      // tile chunk index
            const int row = m / CPR;              // magic-mul
            const int cc  = m - row * CPR;
            const int gy  = min(y0 + row, N - 1);
            const int gc  = min(xc0 + cc, (N >> 2) - 1);
            const float* src = x + ((size_t)gy << 12) + ((size_t)gc << 2);
            gload_lds16(src, tile + (k << 8));
        }
    }

    // uniform-address weight/bias loads (scalar path) overlap staging
    float ws[49];
    #pragma unroll
    for (int i = 0; i < 49; ++i) ws[i] = w[i];
    const float bv = bias[0];

    __syncthreads();   // drains vmcnt before s_barrier

    // ---- compute: thread = (colchunk tau, rowgroup rg); 4-wide x 4-tall ----
    const int tau   = tid & 31;          // cols 4*tau .. 4*tau+3
    const int rg    = tid >> 5;          // rows 4*rg .. 4*rg+3
    const int colf  = tau << 2;
    const int rbase = rg << 2;

    float acc[4][4] = {};

    #pragma unroll
    for (int rr = 0; rr < 10; ++rr) {    // 10 input rows feed 4 output rows
        const float* rp = tile + (rbase + rr) * LDS_W + colf;
        float v[10];
        const float4 a = *reinterpret_cast<const float4*>(rp);
        const float4 b = *reinterpret_cast<const float4*>(rp + 4);
        const float2 c = *reinterpret_cast<const float2*>(rp + 8);
        v[0]=a.x; v[1]=a.y; v[2]=a.z; v[3]=a.w;
        v[4]=b.x; v[5]=b.y; v[6]=b.z; v[7]=b.w;
        v[8]=c.x; v[9]=c.y;

        #pragma unroll
        for (int r = 0; r < 4; ++r) {
            const int ky = rr - r;               // compile-time after unroll
            if (ky >= 0 && ky < 7) {
                #pragma unroll
                for (int kx = 0; kx < 7; ++kx) {
                    const float wk = ws[ky * 7 + kx];
                    #pragma unroll
                    for (int j = 0; j < 4; ++j)
                        acc[r][j] = fmaf(v[kx + j], wk, acc[r][j]);
                }
            }
        }
    }

    // ---- store: unguarded float2 pairs interior, guarded scalar on edges ----
    const int ox  = x0 + colf;
    const int oy0 = y0 + rbase;
    if (ox + 4 <= ON && oy0 + 4 <= ON) {
        #pragma unroll
        for (int r = 0; r < 4; ++r) {
            float* dst = out + (size_t)(oy0 + r) * ON + ox;   // 8B-aligned
            *reinterpret_cast<float2*>(dst)     = make_float2(acc[r][0] + bv, acc[r][1] + bv);
            *reinterpret_cast<float2*>(dst + 2) = make_float2(acc[r][2] + bv, acc[r][3] + bv);
        }
    } else {
        #pragma unroll
        for (int r = 0; r < 4; ++r) {
            const int oy = oy0 + r;
            if (oy < ON) {
                float* dst = out + (size_t)oy * ON;
                #pragma unroll
                for (int j = 0; j < 4; ++j) {
                    const int oxj = ox + j;
                    if (oxj < ON) dst[oxj] = acc[r][j] + bv;
                }
            }
        }
    }
}

extern "C" void kernel_launch(void* const* d_in, const int* in_sizes, int n_in,
                              void* d_out, int out_size, void* d_ws, size_t ws_size,
                              hipStream_t stream) {
    const float* x    = (const float*)d_in[0];
    const float* w    = (const float*)d_in[1];
    const float* bias = (const float*)d_in[2];
    float* out        = (float*)d_out;

    conv7x7_kernel<<<dim3(NWG, 1, 1), dim3(256, 1, 1), 0, stream>>>(x, w, bias, out);
}

// Round 10
// 33.550 us; speedup vs baseline: 1.4592x; 1.0179x over previous
//
#include <hip/hip_runtime.h>

#define N   4096
#define ON  4090
#define LDS_W 136                 // 134 used + pad (rows 16B-aligned)
#define CPR   34                  // float4 chunks per row
#define WBUF  2048                // floats per wave buffer = 8 KB = 8 instr * 256
#define GX  32                    // x tiles (128 wide)
#define GY  512                   // y stripes (8 tall)
#define NT  (GX * GY)             // 16384 wave-tiles
#define NB  (NT / 4)              // 4096 blocks

__device__ __forceinline__ void gload_lds16(const float* g, float* l) {
    __builtin_amdgcn_global_load_lds(
        (const __attribute__((address_space(1))) void*)g,
        (__attribute__((address_space(3))) void*)l,
        16, 0, 0);   // 16 B per lane, dest = uniform base + lane*16
}

// Barrier-free: each wave stages its own 14(+2)x136 input window into a
// private LDS quarter and consumes only that. vmcnt is per-wave, so a single
// s_waitcnt vmcnt(0) replaces __syncthreads; the 4 waves of a block (and the
// 20 waves/CU) are fully independent -> DMA latency hidden by wave TLP.
__global__ __launch_bounds__(256, 5)
void conv7x7_wave(const float* __restrict__ x,
                  const float* __restrict__ w,
                  const float* __restrict__ bias,
                  float* __restrict__ out)
{
    __shared__ float lds[4 * WBUF];   // 32,768 B -> 5 blocks/CU (exactly 160 KiB)

    const int tid  = threadIdx.x;
    const int lane = tid & 63;
    const int wv   = tid >> 6;
    float* buf = lds + (wv << 11);    // wave-private 2048-float region

    // XCD-chunked swizzle (NB % 8 == 0 -> bijective): XCD k owns a contiguous
    // band of 64 stripes -> vertical-halo re-reads hit that XCD's L2.
    const int b  = blockIdx.x;
    const int bs = (b & 7) * (NB / 8) + (b >> 3);
    const int t  = (bs << 2) + wv;    // wave-tile id, row-major over stripes
    const int bx = t & (GX - 1);
    const int by = t >> 5;
    const int x0 = bx << 7;           // tile col base
    const int y0 = by << 3;           // output row base of this 8-row stripe

    // ---- stage 14 used (+2 overshoot) rows x 136 floats, flat chunks ----
    // chunk m -> (row = m/34, cc = m%34); 8 width-16 instrs fill exactly WBUF.
    // Row clamp: only overshoot rows / last stripe engage it; clamped data
    // feeds only store-guarded outputs. Col clamp: only bx=31.
    {
        const int xc0 = x0 >> 2;
        #pragma unroll
        for (int k = 0; k < 8; ++k) {
            const int m   = (k << 6) + lane;
            const int row = m / CPR;               // 0..15
            const int cc  = m - row * CPR;
            const int gy  = min(y0 + row, N - 1);
            const int gc  = min(xc0 + cc, (N >> 2) - 1);
            const float* src = x + ((size_t)gy << 12) + ((size_t)gc << 2);
            gload_lds16(src, buf + (k << 8));
        }
    }

    // uniform-address weight/bias loads (scalar path) overlap the DMA
    float ws[49];
    #pragma unroll
    for (int i = 0; i < 49; ++i) ws[i] = w[i];
    const float bv = bias[0];

    // wave-local drain of the LDS DMA (replaces __syncthreads)
    asm volatile("s_waitcnt vmcnt(0)" ::: "memory");

    // ---- compute: lane = (col chunk tau, row half rg2); 4-wide x 4-tall ----
    // lane-contiguous b128 reads (32 lanes x 16 B) -> conflict-free pattern.
    const int tau   = lane & 31;
    const int rg2   = lane >> 5;         // 0..1 -> rows 0-3 / 4-7 of stripe
    const int colf  = tau << 2;
    const int rbase = rg2 << 2;

    float acc[4][4] = {};

    #pragma unroll
    for (int rr = 0; rr < 10; ++rr) {    // 10 input rows feed 4 output rows
        const float* rp = buf + (rbase + rr) * LDS_W + colf;
        float v[10];
        const float4 a = *reinterpret_cast<const float4*>(rp);
        const float4 bq = *reinterpret_cast<const float4*>(rp + 4);
        const float2 c = *reinterpret_cast<const float2*>(rp + 8);
        v[0]=a.x;  v[1]=a.y;  v[2]=a.z;  v[3]=a.w;
        v[4]=bq.x; v[5]=bq.y; v[6]=bq.z; v[7]=bq.w;
        v[8]=c.x;  v[9]=c.y;

        #pragma unroll
        for (int r = 0; r < 4; ++r) {
            const int ky = rr - r;               // compile-time after unroll
            if (ky >= 0 && ky < 7) {
                #pragma unroll
                for (int kx = 0; kx < 7; ++kx) {
                    const float wk = ws[ky * 7 + kx];
                    #pragma unroll
                    for (int j = 0; j < 4; ++j)
                        acc[r][j] = fmaf(v[kx + j], wk, acc[r][j]);
                }
            }
        }
    }

    // ---- store: unguarded float2 pairs interior, guarded scalar on edges ----
    const int ox  = x0 + colf;
    const int oy0 = y0 + rbase;
    if (ox + 4 <= ON && oy0 + 4 <= ON) {
        #pragma unroll
        for (int r = 0; r < 4; ++r) {
            float* dst = out + (size_t)(oy0 + r) * ON + ox;   // 8B-aligned
            *reinterpret_cast<float2*>(dst)     = make_float2(acc[r][0] + bv, acc[r][1] + bv);
            *reinterpret_cast<float2*>(dst + 2) = make_float2(acc[r][2] + bv, acc[r][3] + bv);
        }
    } else {
        #pragma unroll
        for (int r = 0; r < 4; ++r) {
            const int oy = oy0 + r;
            if (oy < ON) {
                float* dst = out + (size_t)oy * ON;
                #pragma unroll
                for (int j = 0; j < 4; ++j) {
                    const int oxj = ox + j;
                    if (oxj < ON) dst[oxj] = acc[r][j] + bv;
                }
            }
        }
    }
}

extern "C" void kernel_launch(void* const* d_in, const int* in_sizes, int n_in,
                              void* d_out, int out_size, void* d_ws, size_t ws_size,
                              hipStream_t stream) {
    const float* x    = (const float*)d_in[0];
    const float* w    = (const float*)d_in[1];
    const float* bias = (const float*)d_in[2];
    float* out        = (float*)d_out;

    conv7x7_wave<<<dim3(NB, 1, 1), dim3(256, 1, 1), 0, stream>>>(x, w, bias, out);
}